// Round 4
// baseline (467.735 us; speedup 1.0000x reference)
//
#include <hip/hip_runtime.h>
#include <hip/hip_bf16.h>

#define NN 200000
#define ND 128
#define GD 128
#define HID 512
#define NG 1024

typedef __bf16 bf16x8 __attribute__((ext_vector_type(8)));
typedef unsigned short u16x8 __attribute__((ext_vector_type(8)));
typedef float f32x16 __attribute__((ext_vector_type(16)));

// packed-weight bases in bf16 elements inside d_ws
#define PK_WI1 0
#define PK_WI2 131072
#define PK_WJ1 196608
#define PK_WJ2 262144

__device__ __forceinline__ unsigned short f2bf(float x){
  unsigned u = __builtin_bit_cast(unsigned, x);
  u += 0x7FFFu + ((u >> 16) & 1u);          // RNE
  return (unsigned short)(u >> 16);
}
__device__ __forceinline__ float bf2f(unsigned short h){
  return __builtin_bit_cast(float, ((unsigned)h) << 16);
}
__device__ __forceinline__ f32x16 mfma_bf16(u16x8 a, u16x8 b, f32x16 c){
  return __builtin_amdgcn_mfma_f32_32x32x16_bf16(
      __builtin_bit_cast(bf16x8, a), __builtin_bit_cast(bf16x8, b), c, 0, 0, 0);
}

// ---- pack fp32 weights [K][N] -> bf16 B-fragment order for 32x32x16 ----
// frag(kt,nt): lane holds B[kt*16 + (lane>>5)*8 + j][nt*32 + (lane&31)], j=0..7
// flat elem = ((kt*(N/32) + nt)*64 + lane)*8 + j
// Also zeroes the output accumulator (atomics target) — replaces memset.
__global__ void pack_w(const float* __restrict__ Wi1, const float* __restrict__ Wi2,
                       const float* __restrict__ Wj1, const float* __restrict__ Wj2,
                       unsigned short* __restrict__ pk, float* __restrict__ out){
  int g = blockIdx.x * 256 + threadIdx.x;   // 40960 groups of 8 elems
  if (g < 32768) ((float4*)out)[g] = make_float4(0.f, 0.f, 0.f, 0.f); // 131072 floats
  const float* W; int N; int base; int f;
  if (g < 16384)      { W = Wi1; N = 512; base = PK_WI1; f = g; }
  else if (g < 24576) { W = Wi2; N = 128; base = PK_WI2; f = g - 16384; }
  else if (g < 32768) { W = Wj1; N = 512; base = PK_WJ1; f = g - 24576; }
  else                { W = Wj2; N = 128; base = PK_WJ2; f = g - 32768; }
  int lane = f & 63;
  int t = f >> 6;
  int ntiles = N >> 5;
  int nt = t % ntiles, kt = t / ntiles;
  int k0 = kt * 16 + (lane >> 5) * 8;
  int n  = nt * 32 + (lane & 31);
  u16x8 v;
  #pragma unroll
  for (int j = 0; j < 8; ++j) v[j] = f2bf(W[(size_t)(k0 + j) * N + n]);
  *(u16x8*)(pk + base + (size_t)f * 8) = v;
}

// ---- main fused kernel: 4 waves per block, 64 nodes per block ----
// Layer-1: hidden split 4 ways per round (wave w -> n-tile c*4+w); each
//          B-fragment feeds both 32-row tiles. 4 rounds per phase.
// Layer-2: block-shared Ts holds this round's 128 hidden cols; wave w
//          accumulates output n-tile w (cols w*32..w*32+31) over full hidden.
// Gate:    kept in packed-bf16 registers (gacc and jacc share C-layout).
__global__ __launch_bounds__(256, 3)
void readout_main(const float* __restrict__ hT, const float* __restrict__ h0,
                  const int* __restrict__ gi,
                  const float* __restrict__ bi1, const float* __restrict__ bi2,
                  const float* __restrict__ bj1, const float* __restrict__ bj2,
                  const unsigned short* __restrict__ pk,
                  float* __restrict__ out){
  __shared__ __align__(16) unsigned short Xs[64 * 264]; // bf16 [64][256+8]
  __shared__ __align__(16) unsigned short Ts[64 * 136]; // bf16 [64][128+8]
  __shared__ int gids[64];

  const int tid  = threadIdx.x;
  const int lane = tid & 63;
  const int wv   = tid >> 6;                // 0..3
  const int l31  = lane & 31;
  const int q    = lane >> 5;
  const int m0   = blockIdx.x * 64;         // 200000 = 3125*64 exact

  // ---- stage X = [h_T | h_0] as bf16 (all 256 threads, 8 iters) ----
  #pragma unroll
  for (int it = 0; it < 8; ++it){
    int flat = it * 256 + tid;              // 0..2047
    int r  = flat >> 5;                     // 0..63
    int c4 = flat & 31;
    const float4 vT = ((const float4*)(hT + (size_t)(m0 + r) * ND))[c4];
    const float4 v0 = ((const float4*)(h0 + (size_t)(m0 + r) * ND))[c4];
    uint2 pT, p0;
    pT.x = f2bf(vT.x) | ((unsigned)f2bf(vT.y) << 16);
    pT.y = f2bf(vT.z) | ((unsigned)f2bf(vT.w) << 16);
    p0.x = f2bf(v0.x) | ((unsigned)f2bf(v0.y) << 16);
    p0.y = f2bf(v0.z) | ((unsigned)f2bf(v0.w) << 16);
    *(uint2*)&Xs[r * 264 + c4 * 4]       = pT;
    *(uint2*)&Xs[r * 264 + 128 + c4 * 4] = p0;
  }
  if (tid < 64){
    // dtype probe: sorted indices end at 1023 -> int32 layout; int64 high word -> 0
    bool g64 = (gi[NN - 1] == 0);
    gids[tid] = g64 ? gi[2 * (m0 + tid)] : gi[m0 + tid];
  }
  __syncthreads();

  const int aB0 = l31 * 264 + q * 8;        // A-frag row-tile 0
  const int aB1 = (32 + l31) * 264 + q * 8; // A-frag row-tile 1

  f32x16 z;
  #pragma unroll
  for (int i = 0; i < 16; ++i) z[i] = 0.f;

  // ================= phase i: gate = sigmoid(MLP([h_T|h_0])) =================
  f32x16 gacc[2] = {z, z};                  // [row-tile], 32 regs
  for (int c = 0; c < 4; ++c){
    float bb1 = bi1[c * 128 + wv * 32 + l31];
    f32x16 t0 = z, t1 = z;
    #pragma unroll
    for (int half = 0; half < 2; ++half){   // K=256 in two batches of 8
      u16x8 bf[8];
      #pragma unroll
      for (int kt = 0; kt < 8; ++kt){
        int ktg = half * 8 + kt;
        bf[kt] = *(const u16x8*)(pk + PK_WI1 + (size_t)((ktg * 16 + c * 4 + wv) * 64 + lane) * 8);
      }
      #pragma unroll
      for (int kt = 0; kt < 8; ++kt){
        int ktg = half * 8 + kt;
        u16x8 a0 = *(const u16x8*)&Xs[aB0 + ktg * 16];
        u16x8 a1 = *(const u16x8*)&Xs[aB1 + ktg * 16];
        t0 = mfma_bf16(a0, bf[kt], t0);
        t1 = mfma_bf16(a1, bf[kt], t1);
      }
    }
    // layer-2 B prefetch for this round (hidden K-chunk = 128, n-tile = wv)
    u16x8 b2[8];
    #pragma unroll
    for (int ks = 0; ks < 8; ++ks)
      b2[ks] = *(const u16x8*)(pk + PK_WI2 + (size_t)(((c * 8 + ks) * 4 + wv) * 64 + lane) * 8);
    #pragma unroll
    for (int reg = 0; reg < 16; ++reg){     // bias+ReLU, C-layout -> Ts
      int rowl = (reg & 3) + 8 * (reg >> 2) + 4 * q;
      float v0 = t0[reg] + bb1; v0 = v0 > 0.f ? v0 : 0.f;
      float v1 = t1[reg] + bb1; v1 = v1 > 0.f ? v1 : 0.f;
      Ts[rowl * 136 + wv * 32 + l31]        = f2bf(v0);
      Ts[(32 + rowl) * 136 + wv * 32 + l31] = f2bf(v1);
    }
    __syncthreads();                        // Ts complete (all 4 waves)
    #pragma unroll
    for (int mt = 0; mt < 2; ++mt)
      #pragma unroll
      for (int ks = 0; ks < 8; ++ks){
        u16x8 a2 = *(const u16x8*)&Ts[(mt * 32 + l31) * 136 + ks * 16 + q * 8];
        gacc[mt] = mfma_bf16(a2, b2[ks], gacc[mt]);
      }
    __syncthreads();                        // Ts consumed before next round
  }
  // sigmoid -> packed bf16 gate registers (C-layout, col = wv*32 + l31)
  u16x8 gate[2][2];
  {
    float bb2 = bi2[wv * 32 + l31];
    #pragma unroll
    for (int mt = 0; mt < 2; ++mt)
      #pragma unroll
      for (int reg = 0; reg < 16; ++reg){
        float x = gacc[mt][reg] + bb2;
        float s = 1.f / (1.f + __expf(-x));
        gate[mt][reg >> 3][reg & 7] = f2bf(s);
      }
  }

  // ================= phase j: j = MLP(h_T) =================
  f32x16 jacc[2] = {z, z};
  for (int c = 0; c < 4; ++c){
    float bb1 = bj1[c * 128 + wv * 32 + l31];
    f32x16 t0 = z, t1 = z;
    u16x8 bf[8];
    #pragma unroll
    for (int kt = 0; kt < 8; ++kt)          // K=128: one batch
      bf[kt] = *(const u16x8*)(pk + PK_WJ1 + (size_t)((kt * 16 + c * 4 + wv) * 64 + lane) * 8);
    #pragma unroll
    for (int kt = 0; kt < 8; ++kt){
      u16x8 a0 = *(const u16x8*)&Xs[aB0 + kt * 16];
      u16x8 a1 = *(const u16x8*)&Xs[aB1 + kt * 16];
      t0 = mfma_bf16(a0, bf[kt], t0);
      t1 = mfma_bf16(a1, bf[kt], t1);
    }
    u16x8 b2[8];
    #pragma unroll
    for (int ks = 0; ks < 8; ++ks)
      b2[ks] = *(const u16x8*)(pk + PK_WJ2 + (size_t)(((c * 8 + ks) * 4 + wv) * 64 + lane) * 8);
    #pragma unroll
    for (int reg = 0; reg < 16; ++reg){
      int rowl = (reg & 3) + 8 * (reg >> 2) + 4 * q;
      float v0 = t0[reg] + bb1; v0 = v0 > 0.f ? v0 : 0.f;
      float v1 = t1[reg] + bb1; v1 = v1 > 0.f ? v1 : 0.f;
      Ts[rowl * 136 + wv * 32 + l31]        = f2bf(v0);
      Ts[(32 + rowl) * 136 + wv * 32 + l31] = f2bf(v1);
    }
    __syncthreads();
    #pragma unroll
    for (int mt = 0; mt < 2; ++mt)
      #pragma unroll
      for (int ks = 0; ks < 8; ++ks){
        u16x8 a2 = *(const u16x8*)&Ts[(mt * 32 + l31) * 136 + ks * 16 + q * 8];
        jacc[mt] = mfma_bf16(a2, b2[ks], jacc[mt]);
      }
    __syncthreads();
  }

  // ======== epilogue: R_v = gate * (jacc + bj2); sorted-run segmented atomics ========
  // wave w owns cols [w*32, w*32+32); rows visited in ascending order.
  {
    int col = wv * 32 + l31;
    float bb = bj2[col];
    float acc = 0.f; int cg = -1;
    #pragma unroll
    for (int mt = 0; mt < 2; ++mt)
      #pragma unroll
      for (int reg = 0; reg < 16; ++reg){
        int rowl = (reg & 3) + 8 * (reg >> 2) + 4 * q;
        int row = mt * 32 + rowl;
        float g8 = bf2f(gate[mt][reg >> 3][reg & 7]);
        float rv = g8 * (jacc[mt][reg] + bb);
        int g = gids[row];
        if (g != cg){
          if (cg >= 0) atomicAdd(out + (size_t)cg * GD + col, acc);
          acc = 0.f; cg = g;
        }
        acc += rv;
      }
    atomicAdd(out + (size_t)cg * GD + col, acc);
  }
}

extern "C" void kernel_launch(void* const* d_in, const int* in_sizes, int n_in,
                              void* d_out, int out_size, void* d_ws, size_t ws_size,
                              hipStream_t stream){
  const float* hT  = (const float*)d_in[0];
  const float* h0  = (const float*)d_in[1];
  const int*   gi  = (const int*)d_in[2];
  const float* Wi1 = (const float*)d_in[3];
  const float* bi1 = (const float*)d_in[4];
  const float* Wi2 = (const float*)d_in[5];
  const float* bi2 = (const float*)d_in[6];
  const float* Wj1 = (const float*)d_in[7];
  const float* bj1 = (const float*)d_in[8];
  const float* Wj2 = (const float*)d_in[9];
  const float* bj2 = (const float*)d_in[10];
  float* out = (float*)d_out;
  unsigned short* pk = (unsigned short*)d_ws; // needs 655360 B

  pack_w<<<160, 256, 0, stream>>>(Wi1, Wi2, Wj1, Wj2, pk, out);
  readout_main<<<NN / 64, 256, 0, stream>>>(hT, h0, gi, bi1, bi2, bj1, bj2, pk, out);
}

// Round 5
// 369.853 us; speedup vs baseline: 1.2646x; 1.2646x over previous
//
#include <hip/hip_runtime.h>
#include <hip/hip_bf16.h>

#define NN 200000
#define ND 128
#define GD 128
#define HID 512
#define NG 1024

typedef __bf16 bf16x8 __attribute__((ext_vector_type(8)));
typedef unsigned short u16x8 __attribute__((ext_vector_type(8)));
typedef float f32x16 __attribute__((ext_vector_type(16)));

// packed-weight bases in bf16 elements inside d_ws
#define PK_WI1 0
#define PK_WI2 131072
#define PK_WJ1 196608
#define PK_WJ2 262144

__device__ __forceinline__ unsigned short f2bf(float x){
  unsigned u = __builtin_bit_cast(unsigned, x);
  u += 0x7FFFu + ((u >> 16) & 1u);          // RNE
  return (unsigned short)(u >> 16);
}
__device__ __forceinline__ float bf2f(unsigned short h){
  return __builtin_bit_cast(float, ((unsigned)h) << 16);
}
__device__ __forceinline__ f32x16 mfma_bf16(u16x8 a, u16x8 b, f32x16 c){
  return __builtin_amdgcn_mfma_f32_32x32x16_bf16(
      __builtin_bit_cast(bf16x8, a), __builtin_bit_cast(bf16x8, b), c, 0, 0, 0);
}

// ---- pack fp32 weights [K][N] -> bf16 B-fragment order for 32x32x16 ----
// frag(kt,nt): lane holds B[kt*16 + (lane>>5)*8 + j][nt*32 + (lane&31)], j=0..7
// flat elem = ((kt*(N/32) + nt)*64 + lane)*8 + j
// Also zeroes the output accumulator (atomics target) — replaces memset.
__global__ void pack_w(const float* __restrict__ Wi1, const float* __restrict__ Wi2,
                       const float* __restrict__ Wj1, const float* __restrict__ Wj2,
                       unsigned short* __restrict__ pk, float* __restrict__ out){
  int g = blockIdx.x * 256 + threadIdx.x;   // 40960 groups of 8 elems
  if (g < 32768) ((float4*)out)[g] = make_float4(0.f, 0.f, 0.f, 0.f); // 131072 floats
  const float* W; int N; int base; int f;
  if (g < 16384)      { W = Wi1; N = 512; base = PK_WI1; f = g; }
  else if (g < 24576) { W = Wi2; N = 128; base = PK_WI2; f = g - 16384; }
  else if (g < 32768) { W = Wj1; N = 512; base = PK_WJ1; f = g - 24576; }
  else                { W = Wj2; N = 128; base = PK_WJ2; f = g - 32768; }
  int lane = f & 63;
  int t = f >> 6;
  int ntiles = N >> 5;
  int nt = t % ntiles, kt = t / ntiles;
  int k0 = kt * 16 + (lane >> 5) * 8;
  int n  = nt * 32 + (lane & 31);
  u16x8 v;
  #pragma unroll
  for (int j = 0; j < 8; ++j) v[j] = f2bf(W[(size_t)(k0 + j) * N + n]);
  *(u16x8*)(pk + base + (size_t)f * 8) = v;
}

// ---- main fused kernel: 4 waves per block, 64 nodes per block ----
// Register budget is the design constraint (cap 170 @ 3 waves/SIMD):
// transient fragment batches are 4 regs-wide (16 VGPRs) max, layer-2 B loaded
// AFTER the transform (t0/t1 dead), biases fetched per-round.
__global__ __launch_bounds__(256, 3)
void readout_main(const float* __restrict__ hT, const float* __restrict__ h0,
                  const int* __restrict__ gi,
                  const float* __restrict__ bi1, const float* __restrict__ bi2,
                  const float* __restrict__ bj1, const float* __restrict__ bj2,
                  const unsigned short* __restrict__ pk,
                  float* __restrict__ out){
  __shared__ __align__(16) unsigned short Xs[64 * 264]; // bf16 [64][256+8]
  __shared__ __align__(16) unsigned short Ts[64 * 136]; // bf16 [64][128+8]
  __shared__ int gids[64];

  const int tid  = threadIdx.x;
  const int lane = tid & 63;
  const int wv   = tid >> 6;                // 0..3
  const int l31  = lane & 31;
  const int q    = lane >> 5;
  const int m0   = blockIdx.x * 64;         // 200000 = 3125*64 exact

  // ---- stage X = [h_T | h_0] as bf16 (all 256 threads, 8 iters) ----
  #pragma unroll
  for (int it = 0; it < 8; ++it){
    int flat = it * 256 + tid;              // 0..2047
    int r  = flat >> 5;                     // 0..63
    int c4 = flat & 31;
    const float4 vT = ((const float4*)(hT + (size_t)(m0 + r) * ND))[c4];
    const float4 v0 = ((const float4*)(h0 + (size_t)(m0 + r) * ND))[c4];
    uint2 pT, p0;
    pT.x = f2bf(vT.x) | ((unsigned)f2bf(vT.y) << 16);
    pT.y = f2bf(vT.z) | ((unsigned)f2bf(vT.w) << 16);
    p0.x = f2bf(v0.x) | ((unsigned)f2bf(v0.y) << 16);
    p0.y = f2bf(v0.z) | ((unsigned)f2bf(v0.w) << 16);
    *(uint2*)&Xs[r * 264 + c4 * 4]       = pT;
    *(uint2*)&Xs[r * 264 + 128 + c4 * 4] = p0;
  }
  if (tid < 64){
    // dtype probe: sorted indices end at 1023 -> int32 layout; int64 high word -> 0
    bool g64 = (gi[NN - 1] == 0);
    gids[tid] = g64 ? gi[2 * (m0 + tid)] : gi[m0 + tid];
  }
  __syncthreads();

  const int aB0 = l31 * 264 + q * 8;        // A-frag row-tile 0
  const int aB1 = (32 + l31) * 264 + q * 8; // A-frag row-tile 1

  f32x16 z;
  #pragma unroll
  for (int i = 0; i < 16; ++i) z[i] = 0.f;

  // ================= phase i: gate = sigmoid(MLP([h_T|h_0])) =================
  f32x16 gacc[2] = {z, z};                  // [row-tile], 32 regs
  for (int c = 0; c < 4; ++c){
    float bb1 = bi1[c * 128 + wv * 32 + l31];
    f32x16 t0 = z, t1 = z;
    #pragma unroll
    for (int bt = 0; bt < 4; ++bt){         // K=256 in four batches of 4 kt
      u16x8 bf[4];
      #pragma unroll
      for (int kt = 0; kt < 4; ++kt){
        int ktg = bt * 4 + kt;
        bf[kt] = *(const u16x8*)(pk + PK_WI1 + (size_t)((ktg * 16 + c * 4 + wv) * 64 + lane) * 8);
      }
      #pragma unroll
      for (int kt = 0; kt < 4; ++kt){
        int ktg = bt * 4 + kt;
        u16x8 a0 = *(const u16x8*)&Xs[aB0 + ktg * 16];
        u16x8 a1 = *(const u16x8*)&Xs[aB1 + ktg * 16];
        t0 = mfma_bf16(a0, bf[kt], t0);
        t1 = mfma_bf16(a1, bf[kt], t1);
      }
    }
    #pragma unroll
    for (int reg = 0; reg < 16; ++reg){     // bias+ReLU, C-layout -> Ts
      int rowl = (reg & 3) + 8 * (reg >> 2) + 4 * q;
      float v0 = t0[reg] + bb1; v0 = v0 > 0.f ? v0 : 0.f;
      float v1 = t1[reg] + bb1; v1 = v1 > 0.f ? v1 : 0.f;
      Ts[rowl * 136 + wv * 32 + l31]        = f2bf(v0);
      Ts[(32 + rowl) * 136 + wv * 32 + l31] = f2bf(v1);
    }
    __syncthreads();                        // Ts complete (all 4 waves)
    #pragma unroll
    for (int half = 0; half < 2; ++half){   // layer-2 in two batches of 4 ks
      u16x8 b2[4];
      #pragma unroll
      for (int ks = 0; ks < 4; ++ks)
        b2[ks] = *(const u16x8*)(pk + PK_WI2 + (size_t)(((c * 8 + half * 4 + ks) * 4 + wv) * 64 + lane) * 8);
      #pragma unroll
      for (int mt = 0; mt < 2; ++mt)
        #pragma unroll
        for (int ks = 0; ks < 4; ++ks){
          u16x8 a2 = *(const u16x8*)&Ts[(mt * 32 + l31) * 136 + (half * 4 + ks) * 16 + q * 8];
          gacc[mt] = mfma_bf16(a2, b2[ks], gacc[mt]);
        }
    }
    __syncthreads();                        // Ts consumed before next round
  }
  // sigmoid -> packed bf16 gate registers (C-layout, col = wv*32 + l31)
  u16x8 gate[2][2];
  {
    float bb2 = bi2[wv * 32 + l31];
    #pragma unroll
    for (int mt = 0; mt < 2; ++mt)
      #pragma unroll
      for (int reg = 0; reg < 16; ++reg){
        float x = gacc[mt][reg] + bb2;
        float s = 1.f / (1.f + __expf(-x));
        gate[mt][reg >> 3][reg & 7] = f2bf(s);
      }
  }

  // ================= phase j: j = MLP(h_T) =================
  f32x16 jacc[2] = {z, z};
  for (int c = 0; c < 4; ++c){
    float bb1 = bj1[c * 128 + wv * 32 + l31];
    f32x16 t0 = z, t1 = z;
    #pragma unroll
    for (int bt = 0; bt < 2; ++bt){         // K=128 in two batches of 4 kt
      u16x8 bf[4];
      #pragma unroll
      for (int kt = 0; kt < 4; ++kt){
        int ktg = bt * 4 + kt;
        bf[kt] = *(const u16x8*)(pk + PK_WJ1 + (size_t)((ktg * 16 + c * 4 + wv) * 64 + lane) * 8);
      }
      #pragma unroll
      for (int kt = 0; kt < 4; ++kt){
        int ktg = bt * 4 + kt;
        u16x8 a0 = *(const u16x8*)&Xs[aB0 + ktg * 16];
        u16x8 a1 = *(const u16x8*)&Xs[aB1 + ktg * 16];
        t0 = mfma_bf16(a0, bf[kt], t0);
        t1 = mfma_bf16(a1, bf[kt], t1);
      }
    }
    #pragma unroll
    for (int reg = 0; reg < 16; ++reg){
      int rowl = (reg & 3) + 8 * (reg >> 2) + 4 * q;
      float v0 = t0[reg] + bb1; v0 = v0 > 0.f ? v0 : 0.f;
      float v1 = t1[reg] + bb1; v1 = v1 > 0.f ? v1 : 0.f;
      Ts[rowl * 136 + wv * 32 + l31]        = f2bf(v0);
      Ts[(32 + rowl) * 136 + wv * 32 + l31] = f2bf(v1);
    }
    __syncthreads();
    #pragma unroll
    for (int half = 0; half < 2; ++half){
      u16x8 b2[4];
      #pragma unroll
      for (int ks = 0; ks < 4; ++ks)
        b2[ks] = *(const u16x8*)(pk + PK_WJ2 + (size_t)(((c * 8 + half * 4 + ks) * 4 + wv) * 64 + lane) * 8);
      #pragma unroll
      for (int mt = 0; mt < 2; ++mt)
        #pragma unroll
        for (int ks = 0; ks < 4; ++ks){
          u16x8 a2 = *(const u16x8*)&Ts[(mt * 32 + l31) * 136 + (half * 4 + ks) * 16 + q * 8];
          jacc[mt] = mfma_bf16(a2, b2[ks], jacc[mt]);
        }
    }
    __syncthreads();
  }

  // ======== epilogue: R_v = gate * (jacc + bj2); sorted-run segmented atomics ========
  // wave w owns cols [w*32, w*32+32); rows visited in ascending order.
  {
    int col = wv * 32 + l31;
    float bb = bj2[col];
    float acc = 0.f; int cg = -1;
    #pragma unroll
    for (int mt = 0; mt < 2; ++mt)
      #pragma unroll
      for (int reg = 0; reg < 16; ++reg){
        int rowl = (reg & 3) + 8 * (reg >> 2) + 4 * q;
        int row = mt * 32 + rowl;
        float g8 = bf2f(gate[mt][reg >> 3][reg & 7]);
        float rv = g8 * (jacc[mt][reg] + bb);
        int g = gids[row];
        if (g != cg){
          if (cg >= 0) atomicAdd(out + (size_t)cg * GD + col, acc);
          acc = 0.f; cg = g;
        }
        acc += rv;
      }
    atomicAdd(out + (size_t)cg * GD + col, acc);
  }
}

extern "C" void kernel_launch(void* const* d_in, const int* in_sizes, int n_in,
                              void* d_out, int out_size, void* d_ws, size_t ws_size,
                              hipStream_t stream){
  const float* hT  = (const float*)d_in[0];
  const float* h0  = (const float*)d_in[1];
  const int*   gi  = (const int*)d_in[2];
  const float* Wi1 = (const float*)d_in[3];
  const float* bi1 = (const float*)d_in[4];
  const float* Wi2 = (const float*)d_in[5];
  const float* bi2 = (const float*)d_in[6];
  const float* Wj1 = (const float*)d_in[7];
  const float* bj1 = (const float*)d_in[8];
  const float* Wj2 = (const float*)d_in[9];
  const float* bj2 = (const float*)d_in[10];
  float* out = (float*)d_out;
  unsigned short* pk = (unsigned short*)d_ws; // needs 655360 B

  pack_w<<<160, 256, 0, stream>>>(Wi1, Wi2, Wj1, Wj2, pk, out);
  readout_main<<<NN / 64, 256, 0, stream>>>(hT, h0, gi, bi1, bi2, bj1, bj2, pk, out);
}